// Round 16
// baseline (1062.673 us; speedup 1.0000x reference)
//
#include <hip/hip_runtime.h>

#define GROUPS 2
#define VQ 320
#define NCOLS 640            // GROUPS * VQ
#define KDIM 768
#define BM 32                // rows per block
#define BK 8                 // k-tile
#define NT (KDIM / BK)       // 96 k-tiles
#define THREADS 320          // 4 row-groups x 80 col-threads

struct VR { float v; int i; };

union SharedU {
    float ws[2][BK][NCOLS];          // 2 x 20480 B = 40960 B (double-buffered W tile)
    VR red[BM * GROUPS][80];         // 40960 B (epilogue overlay)
};

typedef const __attribute__((address_space(1))) void gvoid_t;
typedef __attribute__((address_space(3))) void lvoid_t;

__global__ __launch_bounds__(THREADS, 4)
void vq_gemm_argmax_gather(const float* __restrict__ x,
                           const float* __restrict__ W,
                           const float* __restrict__ b,
                           const float* __restrict__ cb,
                           float* __restrict__ out)
{
    __shared__ SharedU sh;

    const int t    = threadIdx.x;
    const int c    = t % 80;               // col-thread: cols 4c..4c+3 (+VQ for group 1)
    const int rg   = t / 80;               // row-group: rows 8*rg..8*rg+7
    const int row0 = blockIdx.x * BM;
    const int wave = t >> 6;
    const int lane = t & 63;

    float acc[8][8] = {};

    // W tile for k-rows [tile*8, tile*8+8) x all 640 cols is CONTIGUOUS in W:
    // flat floats [tile*5120, tile*5120+5120). Stage with global_load_lds,
    // lane-linear dest (wave-uniform base + lane*16), 4 instrs/thread.
    const char* wbase = (const char*)W;
    char* lds0 = (char*)&sh.ws[0][0][0];

#define STAGE(buf, tile)                                                        \
    {                                                                           \
        _Pragma("unroll")                                                       \
        for (int i = 0; i < 4; ++i) {                                           \
            int f4 = wave * 64 + i * THREADS;  /* wave-uniform float4 index */  \
            __builtin_amdgcn_global_load_lds(                                   \
                (gvoid_t*)(wbase + (size_t)(tile) * 20480 + (size_t)(f4 + lane) * 16), \
                (lvoid_t*)(lds0 + (size_t)(buf) * 20480 + (size_t)f4 * 16),     \
                16, 0, 0);                                                      \
        }                                                                       \
    }

    STAGE(0, 0);
    __syncthreads();

    int cur = 0;
#pragma unroll 1
    for (int tile = 0; tile < NT; ++tile) {
        if (tile + 1 < NT) STAGE(cur ^ 1, tile + 1);

        const float(*wsl)[NCOLS] = sh.ws[cur];
#pragma unroll
        for (int kt = 0; kt < 2; ++kt) {
            // x fragment: 8 rows x 4 k, quarter-wave-uniform address -> broadcast
            float4 xr[8];
            const float* xp = x + (size_t)(row0 + rg * 8) * KDIM + tile * BK + kt * 4;
#pragma unroll
            for (int r = 0; r < 8; ++r)
                xr[r] = *reinterpret_cast<const float4*>(xp + (size_t)r * KDIM);
#pragma unroll
            for (int kk = 0; kk < 4; ++kk) {
                float4 w0 = *reinterpret_cast<const float4*>(&wsl[kt * 4 + kk][c * 4]);
                float4 w1 = *reinterpret_cast<const float4*>(&wsl[kt * 4 + kk][c * 4 + VQ]);
                float wv[8] = {w0.x, w0.y, w0.z, w0.w, w1.x, w1.y, w1.z, w1.w};
#pragma unroll
                for (int r = 0; r < 8; ++r) {
                    float xv = (&xr[r].x)[kk];
#pragma unroll
                    for (int l = 0; l < 8; ++l)
                        acc[r][l] = fmaf(xv, wv[l], acc[r][l]);
                }
            }
        }
        __syncthreads();     // drains vmcnt (next buf staged) + lgkm; one barrier/tile
        cur ^= 1;
    }

    // ---- epilogue: bias + per-thread argmax, then cross-thread reduction ----
    float bv[8];
    {
        float4 b0 = *reinterpret_cast<const float4*>(&b[c * 4]);
        float4 b1 = *reinterpret_cast<const float4*>(&b[c * 4 + VQ]);
        bv[0] = b0.x; bv[1] = b0.y; bv[2] = b0.z; bv[3] = b0.w;
        bv[4] = b1.x; bv[5] = b1.y; bv[6] = b1.z; bv[7] = b1.w;
    }
#pragma unroll
    for (int r = 0; r < 8; ++r) {
        int row = rg * 8 + r;
        float bestv = acc[r][0] + bv[0]; int besti = c * 4;
#pragma unroll
        for (int l = 1; l < 4; ++l) {
            float v = acc[r][l] + bv[l];
            if (v > bestv || (v == bestv && c * 4 + l < besti)) { bestv = v; besti = c * 4 + l; }
        }
        sh.red[row * 2 + 0][c] = VR{bestv, besti};

        bestv = acc[r][4] + bv[4]; besti = c * 4;
#pragma unroll
        for (int l = 1; l < 4; ++l) {
            float v = acc[r][l + 4] + bv[l + 4];
            if (v > bestv || (v == bestv && c * 4 + l < besti)) { bestv = v; besti = c * 4 + l; }
        }
        sh.red[row * 2 + 1][c] = VR{bestv, besti};
    }
    __syncthreads();

    // 64 reducers, one per (row, group). Rotated scan start -> banks spread.
    // Tie-break is order-independent: (v > best) || (v == best && i < besti).
    if (t < BM * GROUPS) {
        const VR* rr = sh.red[t];
        VR v0 = rr[t % 80];
        float bestv = v0.v; int besti = v0.i;
        for (int i = 1; i < 80; ++i) {
            VR v = rr[(i + t) % 80];
            if (v.v > bestv || (v.v == bestv && v.i < besti)) { bestv = v.v; besti = v.i; }
        }
        sh.red[t][0].i = besti;     // overwrite own slot AFTER full scan
    }
    __syncthreads();

    // ---- gather codebook rows -> out, coalesced float4 ----
    const float4* cb4  = reinterpret_cast<const float4*>(cb);
    float4*       out4 = reinterpret_cast<float4*>(out);
    for (int e = t; e < BM * GROUPS * 32; e += THREADS) {
        int pair = e >> 5, q = e & 31;       // 32 float4 per codebook row
        int row = pair >> 1, g = pair & 1;
        int k = sh.red[pair][0].i;
        out4[(size_t)(row0 + row) * 64 + g * 32 + q] = cb4[(size_t)k * 32 + q];
    }
}

extern "C" void kernel_launch(void* const* d_in, const int* in_sizes, int n_in,
                              void* d_out, int out_size, void* d_ws, size_t ws_size,
                              hipStream_t stream) {
    const float* x  = (const float*)d_in[0];   // [8*4096, 768]
    const float* W  = (const float*)d_in[1];   // [768, 640]
    const float* b  = (const float*)d_in[2];   // [640]
    const float* cb = (const float*)d_in[3];   // [320, 128]
    float* out = (float*)d_out;                // [8*4096, 256]

    const int M = in_sizes[0] / KDIM;          // 32768
    dim3 grid(M / BM);
    dim3 block(THREADS);
    vq_gemm_argmax_gather<<<grid, block, 0, stream>>>(x, W, b, cb, out);
}